// Round 3
// baseline (357.735 us; speedup 1.0000x reference)
//
#include <hip/hip_runtime.h>
#include <hip/hip_bf16.h>

#define T_TOK 4096
#define DDIM  1024
#define HDIM  2048
#define NEXP  8
#define BK 64

typedef __attribute__((ext_vector_type(4))) float f32x4;
typedef __attribute__((ext_vector_type(8))) short s16x8;
typedef __hip_bfloat16 bf16;

typedef const void __attribute__((address_space(1))) gvoid;
typedef void __attribute__((address_space(3))) svoid;

__device__ __forceinline__ void gload16(const void* g, void* l) {
    // async global->LDS, 16B/lane; LDS dest = wave-uniform base, HW adds lane*16
    __builtin_amdgcn_global_load_lds((gvoid*)g, (svoid*)l, 16, 0, 0);
}

// ---------------- router: fp64-accumulated logits, top-2 + softmax ----------------
__global__ void router_kernel(const float* __restrict__ x, const float* __restrict__ rw,
                              int* __restrict__ r_e, float* __restrict__ r_w) {
    int wave = threadIdx.x >> 6, lane = threadIdx.x & 63;
    int t = blockIdx.x * 4 + wave;
    if (t >= T_TOK) return;
    const float* xr = x + (size_t)t * DDIM;
    double acc[NEXP];
#pragma unroll
    for (int e = 0; e < NEXP; ++e) acc[e] = 0.0;
    for (int d = lane; d < DDIM; d += 64) {
        float xv = xr[d];
        const float* rwr = rw + (size_t)d * NEXP;
#pragma unroll
        for (int e = 0; e < NEXP; ++e) acc[e] += (double)xv * (double)rwr[e];
    }
#pragma unroll
    for (int e = 0; e < NEXP; ++e) {
#pragma unroll
        for (int off = 32; off > 0; off >>= 1) acc[e] += __shfl_down(acc[e], off);
    }
    if (lane == 0) {
        int i0 = 0; double v0 = acc[0];
#pragma unroll
        for (int e = 1; e < NEXP; ++e) if (acc[e] > v0) { v0 = acc[e]; i0 = e; }
        int i1 = -1; double v1 = -1e300;
#pragma unroll
        for (int e = 0; e < NEXP; ++e) { if (e == i0) continue; if (acc[e] > v1) { v1 = acc[e]; i1 = e; } }
        float w0 = 1.0f / (1.0f + expf((float)(v1 - v0)));
        float w1 = 1.0f - w0;
        r_e[2*t]   = i0; r_e[2*t+1] = i1;
        r_w[2*t]   = w0; r_w[2*t+1] = w1;
    }
}

// ---------------- binning ----------------
__global__ void count_kernel(const int* __restrict__ r_e, int* __restrict__ cnt) {
    int i = blockIdx.x * blockDim.x + threadIdx.x;
    if (i < 2 * T_TOK) atomicAdd(&cnt[r_e[i]], 1);
}
__global__ void scan_kernel(const int* __restrict__ cnt, int* __restrict__ offs) {
    if (threadIdx.x == 0) {
        int s = 0;
        for (int e = 0; e < NEXP; ++e) { offs[e] = s; s += cnt[e]; }
        offs[NEXP] = s;
    }
}
__global__ void fill_kernel(const int* __restrict__ r_e, const int* __restrict__ offs,
                            int* __restrict__ cnt2, int* __restrict__ list, int* __restrict__ tokslot) {
    int i = blockIdx.x * blockDim.x + threadIdx.x;  // i = 2*t + r
    if (i < 2 * T_TOK) {
        int e = r_e[i];
        int pos = atomicAdd(&cnt2[e], 1);
        int slot = offs[e] + pos;
        list[slot] = i >> 1;
        tokslot[i] = slot;
    }
}

// ---------------- transpose + fp32->bf16 cast (vectorized) ----------------
// in: [R][C] fp32, out: [C][R] bf16; 64x64 tiles, 256 threads
__global__ void transpose_cast_kernel(const float* __restrict__ in, bf16* __restrict__ out,
                                      int R, int C) {
    __shared__ bf16 tile[64][68];   // 136B row stride
    size_t mat = (size_t)blockIdx.z * R * C;
    const float* inp = in + mat;
    bf16* outp = out + mat;
    int r0 = blockIdx.x * 64, c0 = blockIdx.y * 64;
    int tid = threadIdx.x;
#pragma unroll
    for (int i = 0; i < 4; ++i) {
        int idx = i * 256 + tid;
        int r = idx >> 4, c4 = (idx & 15) * 4;
        float4 v = *reinterpret_cast<const float4*>(inp + (size_t)(r0 + r) * C + c0 + c4);
        tile[r][c4 + 0] = __float2bfloat16(v.x);
        tile[r][c4 + 1] = __float2bfloat16(v.y);
        tile[r][c4 + 2] = __float2bfloat16(v.z);
        tile[r][c4 + 3] = __float2bfloat16(v.w);
    }
    __syncthreads();
#pragma unroll
    for (int i = 0; i < 4; ++i) {
        int idx = i * 256 + tid;
        int c = idx >> 4, r4 = (idx & 15) * 4;
        union { ushort4 u; bf16 h[4]; } w;
        w.h[0] = tile[r4 + 0][c];
        w.h[1] = tile[r4 + 1][c];
        w.h[2] = tile[r4 + 2][c];
        w.h[3] = tile[r4 + 3][c];
        *reinterpret_cast<ushort4*>(outp + (size_t)(c0 + c) * R + r0 + r4) = w.u;
    }
}

// ---------------- x -> bf16 cast ----------------
__global__ void cast_x_kernel(const float* __restrict__ x, bf16* __restrict__ xb) {
    size_t i = (size_t)(blockIdx.x * blockDim.x + threadIdx.x) * 4;
    float4 v = *reinterpret_cast<const float4*>(x + i);
    union { ushort4 u; bf16 h[4]; } o;
    o.h[0] = __float2bfloat16(v.x);
    o.h[1] = __float2bfloat16(v.y);
    o.h[2] = __float2bfloat16(v.z);
    o.h[3] = __float2bfloat16(v.w);
    *reinterpret_cast<ushort4*>(xb + i) = o.u;
}

// ======== pass 1: gate+up GEMM, 256x128 tile, 8 waves, 2-phase prefetch dbuf ========
// LDS: A[2][256][64] (64K) + Bg[2][128][64] (32K) + Bu[2][128][64] (32K) = 128 KiB dynamic
__global__ __launch_bounds__(512, 2)
void gateup_kernel(const bf16* __restrict__ xb, const bf16* __restrict__ wgT,
                   const bf16* __restrict__ wuT, const int* __restrict__ offs,
                   const int* __restrict__ list, bf16* __restrict__ hbuf) {
    int e = blockIdx.z;
    int base = offs[e];
    int ne = offs[e + 1] - base;
    int m0 = blockIdx.y * 256;
    if (m0 >= ne) return;
    int n0 = blockIdx.x * 128;

    extern __shared__ __align__(16) char smem[];
    bf16* As  = (bf16*)smem;              // 2 bufs x 16384 elems
    bf16* Bgs = (bf16*)(smem + 65536);    // 2 bufs x 8192
    bf16* Bus = (bf16*)(smem + 98304);    // 2 bufs x 8192

    int tid = threadIdx.x, lane = tid & 63, wid = tid >> 6;
    int sub = lane >> 3, koff = (lane & 7) * 8;

    const bf16* wgp = wgT + ((size_t)e * HDIM + n0) * DDIM;
    const bf16* wup = wuT + ((size_t)e * HDIM + n0) * DDIM;

    // per-thread global source rows (A gathered via token list, clamped; never stored)
    const bf16* aS[4]; const bf16* gS[2]; const bf16* uS[2];
#pragma unroll
    for (int i = 0; i < 4; ++i) {
        int row = i * 64 + wid * 8 + sub;
        int r = m0 + row; if (r > ne - 1) r = ne - 1;
        aS[i] = xb + (size_t)list[base + r] * DDIM + koff;
    }
#pragma unroll
    for (int i = 0; i < 2; ++i) {
        int row = i * 64 + wid * 8 + sub;
        gS[i] = wgp + (size_t)row * DDIM + koff;
        uS[i] = wup + (size_t)row * DDIM + koff;
    }

    int wrow = (wid >> 1) * 64, wcol = (wid & 1) * 64;
    f32x4 zero4 = {0.f, 0.f, 0.f, 0.f};
    f32x4 accg[4][4], accu[4][4];
#pragma unroll
    for (int mi = 0; mi < 4; ++mi)
#pragma unroll
        for (int ni = 0; ni < 4; ++ni) { accg[mi][ni] = zero4; accu[mi][ni] = zero4; }

    int rl = lane & 15, kq = 8 * (lane >> 4);

    // prologue: stage tile 0 into buf 0
    {
        bf16* Ad = As + wid * 512;
        bf16* Gd = Bgs + wid * 512;
        bf16* Ud = Bus + wid * 512;
#pragma unroll
        for (int i = 0; i < 4; ++i) gload16(aS[i], Ad + i * 4096);
#pragma unroll
        for (int i = 0; i < 2; ++i) gload16(gS[i], Gd + i * 4096);
#pragma unroll
        for (int i = 0; i < 2; ++i) gload16(uS[i], Ud + i * 4096);
    }
    __syncthreads();   // drains vmcnt(0): buf0 valid

    const int nk = DDIM / BK;   // 16
    for (int t = 0; t < nk; ++t) {
        int cur = t & 1;
        if (t + 1 < nk) {       // prefetch tile t+1 into the other buffer
            int k0 = (t + 1) * BK;
            bf16* Ad = As + (cur ^ 1) * 16384 + wid * 512;
            bf16* Gd = Bgs + (cur ^ 1) * 8192 + wid * 512;
            bf16* Ud = Bus + (cur ^ 1) * 8192 + wid * 512;
#pragma unroll
            for (int i = 0; i < 4; ++i) gload16(aS[i] + k0, Ad + i * 4096);
#pragma unroll
            for (int i = 0; i < 2; ++i) gload16(gS[i] + k0, Gd + i * 4096);
#pragma unroll
            for (int i = 0; i < 2; ++i) gload16(uS[i] + k0, Ud + i * 4096);
        }
        const bf16* Ab = As + cur * 16384;
        const bf16* Gb = Bgs + cur * 8192;
        const bf16* Ub = Bus + cur * 8192;
#pragma unroll
        for (int ks = 0; ks < 2; ++ks) {
            int ko = ks * 32 + kq;
            s16x8 a[4], bg[4], bu[4];
#pragma unroll
            for (int mi = 0; mi < 4; ++mi)
                a[mi] = *reinterpret_cast<const s16x8*>(Ab + (wrow + mi * 16 + rl) * 64 + ko);
#pragma unroll
            for (int ni = 0; ni < 4; ++ni) {
                bg[ni] = *reinterpret_cast<const s16x8*>(Gb + (wcol + ni * 16 + rl) * 64 + ko);
                bu[ni] = *reinterpret_cast<const s16x8*>(Ub + (wcol + ni * 16 + rl) * 64 + ko);
            }
#pragma unroll
            for (int mi = 0; mi < 4; ++mi)
#pragma unroll
                for (int ni = 0; ni < 4; ++ni) {
                    accg[mi][ni] = __builtin_amdgcn_mfma_f32_16x16x32_bf16(a[mi], bg[ni], accg[mi][ni], 0, 0, 0);
                    accu[mi][ni] = __builtin_amdgcn_mfma_f32_16x16x32_bf16(a[mi], bu[ni], accu[mi][ni], 0, 0, 0);
                }
        }
        // barrier drains vmcnt(0)+lgkmcnt(0): prefetched tile landed, all reads of cur done
        __syncthreads();
    }

    // epilogue: h = silu(g)*u. C/D map: row=(lane>>4)*4+reg, col=lane&15
    int rbase = (lane >> 4) * 4, cbase = lane & 15;
#pragma unroll
    for (int mi = 0; mi < 4; ++mi) {
#pragma unroll
        for (int r = 0; r < 4; ++r) {
            int row = m0 + wrow + mi * 16 + rbase + r;
            if (row < ne) {
                size_t orow = (size_t)(base + row) * HDIM + n0 + wcol + cbase;
#pragma unroll
                for (int ni = 0; ni < 4; ++ni) {
                    float g = accg[mi][ni][r], u = accu[mi][ni][r];
                    float h = (g / (1.0f + expf(-g))) * u;
                    hbuf[orow + ni * 16] = __float2bfloat16(h);
                }
            }
        }
    }
}

// ======== pass 2: down GEMM, 128x256 tile, 8 waves, 2-phase prefetch dbuf ========
// LDS: A[2][128][64] (32K) + B[2][256][64] (64K) = 96 KiB dynamic
__global__ __launch_bounds__(512, 2)
void down_kernel(const bf16* __restrict__ hbuf, const bf16* __restrict__ wdT,
                 const int* __restrict__ offs, float* __restrict__ obuf) {
    int e = blockIdx.z;
    int base = offs[e];
    int ne = offs[e + 1] - base;
    int m0 = blockIdx.y * 128;
    if (m0 >= ne) return;
    int n0 = blockIdx.x * 256;

    extern __shared__ __align__(16) char smem[];
    bf16* As = (bf16*)smem;               // 2 bufs x 8192
    bf16* Bs = (bf16*)(smem + 32768);     // 2 bufs x 16384

    int tid = threadIdx.x, lane = tid & 63, wid = tid >> 6;
    int sub = lane >> 3, koff = (lane & 7) * 8;

    const bf16* wdp = wdT + ((size_t)e * DDIM + n0) * HDIM;

    const bf16* aS[2]; const bf16* bS[4];
#pragma unroll
    for (int i = 0; i < 2; ++i) {
        int row = i * 64 + wid * 8 + sub;
        int r = m0 + row; if (r > ne - 1) r = ne - 1;
        aS[i] = hbuf + (size_t)(base + r) * HDIM + koff;
    }
#pragma unroll
    for (int i = 0; i < 4; ++i) {
        int row = i * 64 + wid * 8 + sub;
        bS[i] = wdp + (size_t)row * HDIM + koff;
    }

    int wrow = (wid >> 2) * 64, wcol = (wid & 3) * 64;
    f32x4 zero4 = {0.f, 0.f, 0.f, 0.f};
    f32x4 acc[4][4];
#pragma unroll
    for (int mi = 0; mi < 4; ++mi)
#pragma unroll
        for (int ni = 0; ni < 4; ++ni) acc[mi][ni] = zero4;

    int rl = lane & 15, kq = 8 * (lane >> 4);

    {
        bf16* Ad = As + wid * 512;
        bf16* Bd = Bs + wid * 512;
#pragma unroll
        for (int i = 0; i < 2; ++i) gload16(aS[i], Ad + i * 4096);
#pragma unroll
        for (int i = 0; i < 4; ++i) gload16(bS[i], Bd + i * 4096);
    }
    __syncthreads();

    const int nk = HDIM / BK;   // 32
    for (int t = 0; t < nk; ++t) {
        int cur = t & 1;
        if (t + 1 < nk) {
            int k0 = (t + 1) * BK;
            bf16* Ad = As + (cur ^ 1) * 8192 + wid * 512;
            bf16* Bd = Bs + (cur ^ 1) * 16384 + wid * 512;
#pragma unroll
            for (int i = 0; i < 2; ++i) gload16(aS[i] + k0, Ad + i * 4096);
#pragma unroll
            for (int i = 0; i < 4; ++i) gload16(bS[i] + k0, Bd + i * 4096);
        }
        const bf16* Ab = As + cur * 8192;
        const bf16* Bb = Bs + cur * 16384;
#pragma unroll
        for (int ks = 0; ks < 2; ++ks) {
            int ko = ks * 32 + kq;
            s16x8 a[4], b[4];
#pragma unroll
            for (int mi = 0; mi < 4; ++mi)
                a[mi] = *reinterpret_cast<const s16x8*>(Ab + (wrow + mi * 16 + rl) * 64 + ko);
#pragma unroll
            for (int ni = 0; ni < 4; ++ni)
                b[ni] = *reinterpret_cast<const s16x8*>(Bb + (wcol + ni * 16 + rl) * 64 + ko);
#pragma unroll
            for (int mi = 0; mi < 4; ++mi)
#pragma unroll
                for (int ni = 0; ni < 4; ++ni)
                    acc[mi][ni] = __builtin_amdgcn_mfma_f32_16x16x32_bf16(a[mi], b[ni], acc[mi][ni], 0, 0, 0);
        }
        __syncthreads();
    }

    int rbase = (lane >> 4) * 4, cbase = lane & 15;
#pragma unroll
    for (int mi = 0; mi < 4; ++mi) {
#pragma unroll
        for (int r = 0; r < 4; ++r) {
            int row = m0 + wrow + mi * 16 + rbase + r;
            if (row < ne) {
                size_t orow = (size_t)(base + row) * DDIM + n0 + wcol + cbase;
#pragma unroll
                for (int ni = 0; ni < 4; ++ni)
                    obuf[orow + ni * 16] = acc[mi][ni][r];
            }
        }
    }
}

// ---------------- combine: y[t] = w0*obuf[slot0] + w1*obuf[slot1] (fixed order) ----------------
__global__ void combine_kernel(const float* __restrict__ obuf, const int* __restrict__ tokslot,
                               const float* __restrict__ r_w, float* __restrict__ y) {
    int i = blockIdx.x * blockDim.x + threadIdx.x;
    int t = i >> 8;            // 256 float4 per token row (D=1024)
    int d4 = (i & 255) * 4;
    float w0 = r_w[2 * t], w1 = r_w[2 * t + 1];
    int s0 = tokslot[2 * t], s1 = tokslot[2 * t + 1];
    float4 a = *reinterpret_cast<const float4*>(obuf + (size_t)s0 * DDIM + d4);
    float4 b = *reinterpret_cast<const float4*>(obuf + (size_t)s1 * DDIM + d4);
    float4 o;
    o.x = w0 * a.x + w1 * b.x;
    o.y = w0 * a.y + w1 * b.y;
    o.z = w0 * a.z + w1 * b.z;
    o.w = w0 * a.w + w1 * b.w;
    *reinterpret_cast<float4*>(y + (size_t)t * DDIM + d4) = o;
}

extern "C" void kernel_launch(void* const* d_in, const int* in_sizes, int n_in,
                              void* d_out, int out_size, void* d_ws, size_t ws_size,
                              hipStream_t stream) {
    const float* x  = (const float*)d_in[0];
    const float* rw = (const float*)d_in[1];
    const float* wg = (const float*)d_in[2];
    const float* wu = (const float*)d_in[3];
    const float* wd = (const float*)d_in[4];
    float* y = (float*)d_out;

    // allow >64KB dynamic LDS (host-side attr set; idempotent, capture-safe)
    hipFuncSetAttribute((const void*)gateup_kernel, hipFuncAttributeMaxDynamicSharedMemorySize, 131072);
    hipFuncSetAttribute((const void*)down_kernel,   hipFuncAttributeMaxDynamicSharedMemorySize, 98304);

    char* ws = (char*)d_ws;
    int*   r_e     = (int*)  (ws + 0);
    float* r_w     = (float*)(ws + 32768);
    int*   cnt     = (int*)  (ws + 65536);
    int*   cnt2    = (int*)  (ws + 65568);
    int*   offs    = (int*)  (ws + 65600);
    int*   list    = (int*)  (ws + 65664);
    int*   tokslot = (int*)  (ws + 98432);
    bf16*  xb      = (bf16*) (ws + (1u << 20));
    bf16*  wgT     = (bf16*) (ws + 9437184ull);
    bf16*  wuT     = (bf16*) (ws + 42991616ull);
    bf16*  wdT     = (bf16*) (ws + 76546048ull);
    bf16*  hbuf    = (bf16*) (ws + 110100480ull);
    float* obuf    = (float*)(ws + 143654912ull);

    // weight transposes + casts
    transpose_cast_kernel<<<dim3(DDIM / 64, HDIM / 64, NEXP), 256, 0, stream>>>(wg, wgT, DDIM, HDIM);
    transpose_cast_kernel<<<dim3(DDIM / 64, HDIM / 64, NEXP), 256, 0, stream>>>(wu, wuT, DDIM, HDIM);
    transpose_cast_kernel<<<dim3(HDIM / 64, DDIM / 64, NEXP), 256, 0, stream>>>(wd, wdT, HDIM, DDIM);
    cast_x_kernel<<<dim3(T_TOK * DDIM / 4 / 256), 256, 0, stream>>>(x, xb);

    // routing
    router_kernel<<<dim3(T_TOK / 4), 256, 0, stream>>>(x, rw, r_e, r_w);
    hipMemsetAsync(ws + 65536, 0, 64, stream);  // cnt + cnt2
    count_kernel<<<dim3(2 * T_TOK / 256), 256, 0, stream>>>(r_e, cnt);
    scan_kernel<<<dim3(1), 64, 0, stream>>>(cnt, offs);
    fill_kernel<<<dim3(2 * T_TOK / 256), 256, 0, stream>>>(r_e, offs, cnt2, list, tokslot);

    // expert GEMMs (grouped, worst-case grid with early-exit)
    gateup_kernel<<<dim3(HDIM / 128, T_TOK / 256, NEXP), 512, 131072, stream>>>(xb, wgT, wuT, offs, list, hbuf);
    down_kernel<<<dim3(DDIM / 256, T_TOK / 128, NEXP), 512, 98304, stream>>>(hbuf, wdT, offs, obuf);

    // combine
    combine_kernel<<<dim3(T_TOK * DDIM / 4 / 256), 256, 0, stream>>>(obuf, tokslot, r_w, y);
}

// Round 4
// 329.929 us; speedup vs baseline: 1.0843x; 1.0843x over previous
//
#include <hip/hip_runtime.h>
#include <hip/hip_bf16.h>

#define T_TOK 4096
#define DDIM  1024
#define HDIM  2048
#define NEXP  8
#define BK 64

typedef __attribute__((ext_vector_type(4))) float f32x4;
typedef __attribute__((ext_vector_type(8))) short s16x8;
typedef __hip_bfloat16 bf16;

typedef const void __attribute__((address_space(1))) gvoid;
typedef void __attribute__((address_space(3))) svoid;

__device__ __forceinline__ void gload16(const void* g, void* l) {
    // async global->LDS, 16B/lane; LDS dest = wave-uniform base, HW adds lane*16
    __builtin_amdgcn_global_load_lds((gvoid*)g, (svoid*)l, 16, 0, 0);
}

// ---------------- router: fp64-accumulated logits, top-2 + softmax ----------------
__global__ void router_kernel(const float* __restrict__ x, const float* __restrict__ rw,
                              int* __restrict__ r_e, float* __restrict__ r_w) {
    int wave = threadIdx.x >> 6, lane = threadIdx.x & 63;
    int t = blockIdx.x * 4 + wave;
    if (t >= T_TOK) return;
    const float* xr = x + (size_t)t * DDIM;
    double acc[NEXP];
#pragma unroll
    for (int e = 0; e < NEXP; ++e) acc[e] = 0.0;
    for (int d = lane; d < DDIM; d += 64) {
        float xv = xr[d];
        const float* rwr = rw + (size_t)d * NEXP;
#pragma unroll
        for (int e = 0; e < NEXP; ++e) acc[e] += (double)xv * (double)rwr[e];
    }
#pragma unroll
    for (int e = 0; e < NEXP; ++e) {
#pragma unroll
        for (int off = 32; off > 0; off >>= 1) acc[e] += __shfl_down(acc[e], off);
    }
    if (lane == 0) {
        int i0 = 0; double v0 = acc[0];
#pragma unroll
        for (int e = 1; e < NEXP; ++e) if (acc[e] > v0) { v0 = acc[e]; i0 = e; }
        int i1 = -1; double v1 = -1e300;
#pragma unroll
        for (int e = 0; e < NEXP; ++e) { if (e == i0) continue; if (acc[e] > v1) { v1 = acc[e]; i1 = e; } }
        float w0 = 1.0f / (1.0f + expf((float)(v1 - v0)));
        float w1 = 1.0f - w0;
        r_e[2*t]   = i0; r_e[2*t+1] = i1;
        r_w[2*t]   = w0; r_w[2*t+1] = w1;
    }
}

// ---------------- binning ----------------
__global__ void count_kernel(const int* __restrict__ r_e, int* __restrict__ cnt) {
    int i = blockIdx.x * blockDim.x + threadIdx.x;
    if (i < 2 * T_TOK) atomicAdd(&cnt[r_e[i]], 1);
}
__global__ void scan_kernel(const int* __restrict__ cnt, int* __restrict__ offs) {
    if (threadIdx.x == 0) {
        int s = 0;
        for (int e = 0; e < NEXP; ++e) { offs[e] = s; s += cnt[e]; }
        offs[NEXP] = s;
    }
}
__global__ void fill_kernel(const int* __restrict__ r_e, const int* __restrict__ offs,
                            int* __restrict__ cnt2, const float* __restrict__ r_w,
                            int* __restrict__ list, float* __restrict__ slot_w) {
    int i = blockIdx.x * blockDim.x + threadIdx.x;  // i = 2*t + r
    if (i < 2 * T_TOK) {
        int e = r_e[i];
        int pos = atomicAdd(&cnt2[e], 1);
        int slot = offs[e] + pos;
        list[slot] = i >> 1;
        slot_w[slot] = r_w[i];
    }
}

// ---------------- transpose + fp32->bf16 cast (vectorized, generalized) ----------------
// in: [z][R][C] fp32; out column c -> out[z*outE + ((c*rmul)+roff)*R + r]  (bf16)
__global__ void transpose_cast_kernel(const float* __restrict__ in, bf16* __restrict__ out,
                                      int R, int C, int rmul, int roff, size_t outE) {
    __shared__ bf16 tile[64][68];
    const float* inp = in + (size_t)blockIdx.z * R * C;
    bf16* outp = out + (size_t)blockIdx.z * outE;
    int r0 = blockIdx.x * 64, c0 = blockIdx.y * 64;
    int tid = threadIdx.x;
#pragma unroll
    for (int i = 0; i < 4; ++i) {
        int idx = i * 256 + tid;
        int r = idx >> 4, c4 = (idx & 15) * 4;
        float4 v = *reinterpret_cast<const float4*>(inp + (size_t)(r0 + r) * C + c0 + c4);
        tile[r][c4 + 0] = __float2bfloat16(v.x);
        tile[r][c4 + 1] = __float2bfloat16(v.y);
        tile[r][c4 + 2] = __float2bfloat16(v.z);
        tile[r][c4 + 3] = __float2bfloat16(v.w);
    }
    __syncthreads();
#pragma unroll
    for (int i = 0; i < 4; ++i) {
        int idx = i * 256 + tid;
        int c = idx >> 4, r4 = (idx & 15) * 4;
        union { ushort4 u; bf16 h[4]; } w;
        w.h[0] = tile[r4 + 0][c];
        w.h[1] = tile[r4 + 1][c];
        w.h[2] = tile[r4 + 2][c];
        w.h[3] = tile[r4 + 3][c];
        *reinterpret_cast<ushort4*>(outp + ((size_t)(c0 + c) * rmul + roff) * R + r0 + r4) = w.u;
    }
}

// ---------------- x -> bf16 cast ----------------
__global__ void cast_x_kernel(const float* __restrict__ x, bf16* __restrict__ xb) {
    size_t i = (size_t)(blockIdx.x * blockDim.x + threadIdx.x) * 4;
    float4 v = *reinterpret_cast<const float4*>(x + i);
    union { ushort4 u; bf16 h[4]; } o;
    o.h[0] = __float2bfloat16(v.x);
    o.h[1] = __float2bfloat16(v.y);
    o.h[2] = __float2bfloat16(v.z);
    o.h[3] = __float2bfloat16(v.w);
    *reinterpret_cast<ushort4*>(xb + i) = o.u;
}

// ======== pass 1: gate+up as ONE plain GEMM over interleaved wguT [2H][D] ========
// 128x128 tile, BK=64, 512 thr (8 waves, 2M x 4N), counted-vmcnt dbuf, XOR-swizzled LDS.
// Epilogue pairs even(gate)/odd(up) columns via shfl_xor(1): h = silu(g)*u -> hbuf.
__global__ __launch_bounds__(512, 4)
void gateup_kernel(const bf16* __restrict__ xb, const bf16* __restrict__ wguT,
                   const int* __restrict__ offs, const int* __restrict__ list,
                   bf16* __restrict__ hbuf) {
    int e = blockIdx.z;
    int base = offs[e];
    int ne = offs[e + 1] - base;
    int m0 = blockIdx.y * 128;
    if (m0 >= ne) return;
    int n0 = blockIdx.x * 128;   // in 2H=4096 interleaved space

    __shared__ bf16 As[2][128 * 64];   // 2 x 16 KB
    __shared__ bf16 Bs[2][128 * 64];   // 2 x 16 KB   (total 64 KB -> 2 blocks/CU)

    int tid = threadIdx.x, lane = tid & 63, wid = tid >> 6;
    int sub = lane >> 3;
    int swz = 8 * ((lane & 7) ^ sub);   // inverse-swizzled source chunk (rule #21)

    const bf16* bbase = wguT + (size_t)e * (2 * HDIM) * DDIM + (size_t)n0 * DDIM;

    // per-thread global sources (2 A-rows + 2 B-rows, 16B each per K-tile)
    const bf16* aS[2]; const bf16* bS[2];
#pragma unroll
    for (int i = 0; i < 2; ++i) {
        int row = i * 64 + wid * 8 + sub;
        int r = m0 + row; if (r > ne - 1) r = ne - 1;          // clamp: read-only, never stored
        aS[i] = xb + (size_t)list[base + r] * DDIM + swz;
        bS[i] = bbase + (size_t)row * DDIM + swz;
    }
    int dst0 = (wid * 8) * 64, dst1 = (64 + wid * 8) * 64;     // wave-uniform LDS elem offsets

    int wrow = (wid >> 2) * 64;      // 2 M-wave rows
    int wcol = (wid & 3) * 32;       // 4 N-wave cols
    int rl = lane & 15, kq = 8 * (lane >> 4);
    int xorv = (rl & 7) * 8;         // read-side swizzle (same involution as source)

    f32x4 zero4 = {0.f, 0.f, 0.f, 0.f};
    f32x4 acc[4][2];
#pragma unroll
    for (int mi = 0; mi < 4; ++mi) { acc[mi][0] = zero4; acc[mi][1] = zero4; }

    const int nk = DDIM / BK;   // 16

    // prologue: stage tiles 0 (oldest) then 1 -> 8 outstanding loads/wave
    gload16(aS[0], &As[0][dst0]);
    gload16(aS[1], &As[0][dst1]);
    gload16(bS[0], &Bs[0][dst0]);
    gload16(bS[1], &Bs[0][dst1]);
    gload16(aS[0] + BK, &As[1][dst0]);
    gload16(aS[1] + BK, &As[1][dst1]);
    gload16(bS[0] + BK, &Bs[1][dst0]);
    gload16(bS[1] + BK, &Bs[1][dst1]);

#define GU_COMPUTE(Ab, Bb)                                                        \
    _Pragma("unroll")                                                             \
    for (int kk = 0; kk < 2; ++kk) {                                              \
        int kos = (kk * 32 + kq) ^ xorv;                                          \
        s16x8 a[4], b[2];                                                         \
        _Pragma("unroll")                                                         \
        for (int mi = 0; mi < 4; ++mi)                                            \
            a[mi] = *reinterpret_cast<const s16x8*>(&(Ab)[(wrow + mi * 16 + rl) * 64 + kos]); \
        _Pragma("unroll")                                                         \
        for (int ni = 0; ni < 2; ++ni)                                            \
            b[ni] = *reinterpret_cast<const s16x8*>(&(Bb)[(wcol + ni * 16 + rl) * 64 + kos]); \
        _Pragma("unroll")                                                         \
        for (int mi = 0; mi < 4; ++mi)                                            \
            _Pragma("unroll")                                                     \
            for (int ni = 0; ni < 2; ++ni)                                        \
                acc[mi][ni] = __builtin_amdgcn_mfma_f32_16x16x32_bf16(a[mi], b[ni], acc[mi][ni], 0, 0, 0); \
    }

    for (int t = 0; t < nk - 1; ++t) {
        asm volatile("s_waitcnt vmcnt(4)" ::: "memory");   // tile t landed; t+1 stays in flight
        __builtin_amdgcn_s_barrier();
        GU_COMPUTE(As[t & 1], Bs[t & 1]);
        __builtin_amdgcn_sched_barrier(0);
        __builtin_amdgcn_s_barrier();                      // all waves done reading buf[t&1]
        if (t + 2 < nk) {
            int k0 = (t + 2) * BK;
            gload16(aS[0] + k0, &As[t & 1][dst0]);
            gload16(aS[1] + k0, &As[t & 1][dst1]);
            gload16(bS[0] + k0, &Bs[t & 1][dst0]);
            gload16(bS[1] + k0, &Bs[t & 1][dst1]);
        }
    }
    asm volatile("s_waitcnt vmcnt(0)" ::: "memory");
    __builtin_amdgcn_s_barrier();
    GU_COMPUTE(As[(nk - 1) & 1], Bs[(nk - 1) & 1]);
#undef GU_COMPUTE

    // epilogue: even col = gate(h), odd col = up(h); pair via shfl_xor(1), even lanes store.
    int rbase = (lane >> 4) * 4, cbase = lane & 15;
    bool evenlane = (lane & 1) == 0;
#pragma unroll
    for (int mi = 0; mi < 4; ++mi) {
#pragma unroll
        for (int ni = 0; ni < 2; ++ni) {
#pragma unroll
            for (int r = 0; r < 4; ++r) {
                float own = acc[mi][ni][r];
                float oth = __shfl_xor(own, 1);
                int row = m0 + wrow + mi * 16 + rbase + r;
                if (evenlane && row < ne) {
                    float g = own, u = oth;
                    float h = (g / (1.0f + expf(-g))) * u;
                    int hcol = (n0 + wcol + ni * 16 + cbase) >> 1;
                    hbuf[(size_t)(base + row) * HDIM + hcol] = __float2bfloat16(h);
                }
            }
        }
    }
}

// ======== pass 2: down GEMM, fused combine via deterministic atomicAdd into y ========
// 128x128 tile, BK=64, counted-vmcnt dbuf, XOR-swizzled LDS. y must be zeroed first;
// each y element receives exactly 2 commutative fp32 adds -> bitwise deterministic.
__global__ __launch_bounds__(512, 4)
void down_kernel(const bf16* __restrict__ hbuf, const bf16* __restrict__ wdT,
                 const int* __restrict__ offs, const int* __restrict__ list,
                 const float* __restrict__ slot_w, float* __restrict__ y) {
    int e = blockIdx.z;
    int base = offs[e];
    int ne = offs[e + 1] - base;
    int m0 = blockIdx.y * 128;
    if (m0 >= ne) return;
    int n0 = blockIdx.x * 128;   // d-tile

    __shared__ bf16 As[2][128 * 64];
    __shared__ bf16 Bs[2][128 * 64];

    int tid = threadIdx.x, lane = tid & 63, wid = tid >> 6;
    int sub = lane >> 3;
    int swz = 8 * ((lane & 7) ^ sub);

    const bf16* bbase = wdT + (size_t)e * DDIM * HDIM + (size_t)n0 * HDIM;

    const bf16* aS[2]; const bf16* bS[2];
#pragma unroll
    for (int i = 0; i < 2; ++i) {
        int row = i * 64 + wid * 8 + sub;
        int r = m0 + row; if (r > ne - 1) r = ne - 1;
        aS[i] = hbuf + (size_t)(base + r) * HDIM + swz;
        bS[i] = bbase + (size_t)row * HDIM + swz;
    }
    int dst0 = (wid * 8) * 64, dst1 = (64 + wid * 8) * 64;

    int wrow = (wid >> 2) * 64;
    int wcol = (wid & 3) * 32;
    int rl = lane & 15, kq = 8 * (lane >> 4);
    int xorv = (rl & 7) * 8;

    f32x4 zero4 = {0.f, 0.f, 0.f, 0.f};
    f32x4 acc[4][2];
#pragma unroll
    for (int mi = 0; mi < 4; ++mi) { acc[mi][0] = zero4; acc[mi][1] = zero4; }

    const int nk = HDIM / BK;   // 32

    gload16(aS[0], &As[0][dst0]);
    gload16(aS[1], &As[0][dst1]);
    gload16(bS[0], &Bs[0][dst0]);
    gload16(bS[1], &Bs[0][dst1]);
    gload16(aS[0] + BK, &As[1][dst0]);
    gload16(aS[1] + BK, &As[1][dst1]);
    gload16(bS[0] + BK, &Bs[1][dst0]);
    gload16(bS[1] + BK, &Bs[1][dst1]);

#define DN_COMPUTE(Ab, Bb)                                                        \
    _Pragma("unroll")                                                             \
    for (int kk = 0; kk < 2; ++kk) {                                              \
        int kos = (kk * 32 + kq) ^ xorv;                                          \
        s16x8 a[4], b[2];                                                         \
        _Pragma("unroll")                                                         \
        for (int mi = 0; mi < 4; ++mi)                                            \
            a[mi] = *reinterpret_cast<const s16x8*>(&(Ab)[(wrow + mi * 16 + rl) * 64 + kos]); \
        _Pragma("unroll")                                                         \
        for (int ni = 0; ni < 2; ++ni)                                            \
            b[ni] = *reinterpret_cast<const s16x8*>(&(Bb)[(wcol + ni * 16 + rl) * 64 + kos]); \
        _Pragma("unroll")                                                         \
        for (int mi = 0; mi < 4; ++mi)                                            \
            _Pragma("unroll")                                                     \
            for (int ni = 0; ni < 2; ++ni)                                        \
                acc[mi][ni] = __builtin_amdgcn_mfma_f32_16x16x32_bf16(a[mi], b[ni], acc[mi][ni], 0, 0, 0); \
    }

    for (int t = 0; t < nk - 1; ++t) {
        asm volatile("s_waitcnt vmcnt(4)" ::: "memory");
        __builtin_amdgcn_s_barrier();
        DN_COMPUTE(As[t & 1], Bs[t & 1]);
        __builtin_amdgcn_sched_barrier(0);
        __builtin_amdgcn_s_barrier();
        if (t + 2 < nk) {
            int k0 = (t + 2) * BK;
            gload16(aS[0] + k0, &As[t & 1][dst0]);
            gload16(aS[1] + k0, &As[t & 1][dst1]);
            gload16(bS[0] + k0, &Bs[t & 1][dst0]);
            gload16(bS[1] + k0, &Bs[t & 1][dst1]);
        }
    }
    asm volatile("s_waitcnt vmcnt(0)" ::: "memory");
    __builtin_amdgcn_s_barrier();
    DN_COMPUTE(As[(nk - 1) & 1], Bs[(nk - 1) & 1]);
#undef DN_COMPUTE

    // epilogue: y[tok][col] += w * acc  (exactly 2 adds per element, commutative -> deterministic)
    int rbase = (lane >> 4) * 4, cbase = lane & 15;
#pragma unroll
    for (int mi = 0; mi < 4; ++mi) {
#pragma unroll
        for (int r = 0; r < 4; ++r) {
            int row = m0 + wrow + mi * 16 + rbase + r;
            if (row < ne) {
                int slot = base + row;
                int tok = list[slot];
                float w = slot_w[slot];
                float* yrow = y + (size_t)tok * DDIM + n0 + wcol + cbase;
#pragma unroll
                for (int ni = 0; ni < 2; ++ni)
                    atomicAdd(yrow + ni * 16, w * acc[mi][ni][r]);
            }
        }
    }
}

extern "C" void kernel_launch(void* const* d_in, const int* in_sizes, int n_in,
                              void* d_out, int out_size, void* d_ws, size_t ws_size,
                              hipStream_t stream) {
    const float* x  = (const float*)d_in[0];
    const float* rw = (const float*)d_in[1];
    const float* wg = (const float*)d_in[2];
    const float* wu = (const float*)d_in[3];
    const float* wd = (const float*)d_in[4];
    float* y = (float*)d_out;

    char* ws = (char*)d_ws;
    int*   r_e    = (int*)  (ws + 0);           // 2T ints
    float* r_w    = (float*)(ws + 32768);       // 2T floats
    int*   cnt    = (int*)  (ws + 65536);       // 8
    int*   cnt2   = (int*)  (ws + 65568);       // 8
    int*   offs   = (int*)  (ws + 65600);       // 9
    int*   list   = (int*)  (ws + 65664);       // 2T ints
    float* slot_w = (float*)(ws + 98432);       // 2T floats
    bf16*  xb     = (bf16*) (ws + 1048576ull);      // 8 MB
    bf16*  wguT   = (bf16*) (ws + 16777216ull);     // 64 MB  [E][2H][D] interleaved g/u
    bf16*  wdT    = (bf16*) (ws + 83886080ull);     // 32 MB  [E][D][H]
    bf16*  hbuf   = (bf16*) (ws + 117440512ull);    // 32 MB  [slot][H]  (end ~150 MB)

    // weight transposes + casts (wg/wu interleaved into wguT rows 2h / 2h+1)
    transpose_cast_kernel<<<dim3(DDIM / 64, HDIM / 64, NEXP), 256, 0, stream>>>(
        wg, wguT, DDIM, HDIM, 2, 0, (size_t)2 * HDIM * DDIM);
    transpose_cast_kernel<<<dim3(DDIM / 64, HDIM / 64, NEXP), 256, 0, stream>>>(
        wu, wguT, DDIM, HDIM, 2, 1, (size_t)2 * HDIM * DDIM);
    transpose_cast_kernel<<<dim3(HDIM / 64, DDIM / 64, NEXP), 256, 0, stream>>>(
        wd, wdT, HDIM, DDIM, 1, 0, (size_t)DDIM * HDIM);
    cast_x_kernel<<<dim3(T_TOK * DDIM / 4 / 256), 256, 0, stream>>>(x, xb);

    // routing
    router_kernel<<<dim3(T_TOK / 4), 256, 0, stream>>>(x, rw, r_e, r_w);
    hipMemsetAsync(ws + 65536, 0, 64, stream);  // cnt + cnt2
    count_kernel<<<dim3(2 * T_TOK / 256), 256, 0, stream>>>(r_e, cnt);
    scan_kernel<<<dim3(1), 64, 0, stream>>>(cnt, offs);
    fill_kernel<<<dim3(2 * T_TOK / 256), 256, 0, stream>>>(r_e, offs, cnt2, r_w, list, slot_w);

    // zero y (down accumulates into it atomically)
    hipMemsetAsync(d_out, 0, (size_t)out_size * sizeof(float), stream);

    // expert GEMMs (grouped, worst-case grid with early-exit)
    gateup_kernel<<<dim3(2 * HDIM / 128, T_TOK / 128, NEXP), 512, 0, stream>>>(xb, wguT, offs, list, hbuf);
    down_kernel<<<dim3(DDIM / 128, T_TOK / 128, NEXP), 512, 0, stream>>>(hbuf, wdT, offs, list, slot_w, y);
}